// Round 21
// baseline (349.644 us; speedup 1.0000x reference)
//
#include <hip/hip_runtime.h>

#define NN 50000
#define NE 800000
#define D 64
#define SLICE 64                        // dst nodes per slice block
#define NBLK 782                        // ceil(NN/SLICE) = buckets
#define BCAP 1536                       // per-bucket capacity (mean 1024, >15 sigma)
#define CSTRIDE 4                       // cursor padding: 16 B
#define UVNODES 64                      // nodes per uv block (8 per wave, 8 waves)
#define UVBLK 782                       // ceil(NN/UVNODES)
#define BINBLK 98                       // fat bin blocks (8192 edges each)
#define EPB 8192                        // edges per bin block
#define SCRTOT 2304                     // sorted-list capacity
#define CURWORDS (NBLK * CSTRIDE)       // 3128 dwords
#define WS 68                           // W^T row stride (floats); f32x4 reads -> contiguous-b128 bank pattern

typedef int i32x4 __attribute__((ext_vector_type(4)));
typedef float f32x4 __attribute__((ext_vector_type(4)));
typedef unsigned short u16x8 __attribute__((ext_vector_type(8)));

__device__ __forceinline__ float b2f(unsigned short h) {
    unsigned int u = ((unsigned int)h) << 16;
    return __builtin_bit_cast(float, u);
}
__device__ __forceinline__ unsigned short f2bf(float f) {
    unsigned int u = __builtin_bit_cast(unsigned int, f);
    u = (u + 0x7fffu + ((u >> 16) & 1u)) >> 16;
    return (unsigned short)u;
}

// ---------------------------------------------------------------------------
// zero_cursor: zeroes the per-bucket cursors.
// ---------------------------------------------------------------------------
__global__ __launch_bounds__(256) void zero_cursor(unsigned int* __restrict__ cursor)
{
    int i = blockIdx.x * 256 + threadIdx.x;
    if (i < CURWORDS) cursor[i] = 0u;
}

// ---------------------------------------------------------------------------
// pre_fused (512 threads): blocks [0, UVBLK) = uv/res GEMMs.
//   W^T in LDS, stride 68, read f32x4 (one read = 4 k's; bank starts
//   4(l+q)%32 = contiguous-b128 pattern, 85 B/cyc). x staged as bf16:
//   one uniform u16x8 read per k broadcasts all 8 nodes. Per k:
//   0.75 + 1 b128 = ~21 cyc per 8 nodes (was 29.4 per 4). No readlane.
// Blocks [UVBLK, ..) = histogram binning (512-thread variant).
// LDS: 3 x 64*68 f32 (51K) + xs bf16 8K = 59 KB -> 2 blocks/CU, 16 waves.
// ---------------------------------------------------------------------------
__global__ __launch_bounds__(512) void pre_fused(
    const float* __restrict__ x,
    const int* __restrict__ ei,
    const float* __restrict__ W_edge,
    const float* __restrict__ b_edge,
    const float* __restrict__ W_res,
    const float* __restrict__ b_res,
    unsigned short* __restrict__ u,
    unsigned short* __restrict__ v,
    unsigned short* __restrict__ res,
    unsigned int* __restrict__ bins,
    unsigned int* __restrict__ cursor)
{
    __shared__ float WuT[D * WS];           // (Wtop-Wbot)^T [c][k] | bin: hist/fill
    __shared__ float WvT[D * WS];           // Wbot^T               | bin: base
    __shared__ float WrT[D * WS];           // W_res^T
    __shared__ unsigned short xs[8][D][8];  // [wave][k][node] bf16 (8 KB)

    const int tid  = threadIdx.x;
    const int lane = tid & 63;
    const int wid  = tid >> 6;              // 0..7

    if (blockIdx.x < UVBLK) {
        // stage W transposed (coalesced global reads; scatter LDS writes, one-time)
        for (int i = tid; i < D * D; i += 512) {
            int k = i >> 6, c = i & 63;
            float wt = W_edge[i], wb = W_edge[D * D + i];
            WuT[c * WS + k] = wt - wb;
            WvT[c * WS + k] = wb;
            WrT[c * WS + k] = W_res[i];
        }

        // stage x rows as bf16: lane l holds x[n0+j][l]; pack 8 -> one b128 write
        const int n0  = blockIdx.x * UVNODES + wid * 8;
        const int n0c = (n0 <= NN - 8) ? n0 : (NN - 8);
        {
            u16x8 px;
#pragma unroll
            for (int j = 0; j < 8; ++j)
                px[j] = f2bf(x[(size_t)(n0c + j) * D + lane]);
            *(u16x8*)&xs[wid][lane][0] = px;
        }
        __syncthreads();     // W ready (xs is wave-private; barrier covers both)

        const float be = b_edge[lane];
        const float br = b_res[lane];
        float au[8], av[8], ar[8];
#pragma unroll
        for (int j = 0; j < 8; ++j) { au[j] = be; av[j] = 0.f; ar[j] = br; }

#pragma unroll
        for (int kq = 0; kq < 16; ++kq) {
            f32x4 wu = *(const f32x4*)&WuT[lane * WS + 4 * kq];
            f32x4 wv = *(const f32x4*)&WvT[lane * WS + 4 * kq];
            f32x4 wr = *(const f32x4*)&WrT[lane * WS + 4 * kq];
#pragma unroll
            for (int t = 0; t < 4; ++t) {
                u16x8 xh = *(const u16x8*)&xs[wid][4 * kq + t][0];  // uniform
#pragma unroll
                for (int j = 0; j < 8; ++j) {
                    float s = b2f(xh[j]);
                    au[j] += s * wu[t];
                    av[j] += s * wv[t];
                    ar[j] += s * wr[t];
                }
            }
        }

        if (n0 < NN) {   // NN % 8 == 0 -> all 8 valid when n0 < NN
#pragma unroll
            for (int j = 0; j < 8; ++j) {
                u[(size_t)(n0 + j) * D + lane]   = f2bf(au[j]);
                v[(size_t)(n0 + j) * D + lane]   = f2bf(av[j]);
                res[(size_t)(n0 + j) * D + lane] = f2bf(ar[j]);
            }
        }
    } else {
        // ---- histogram binning (512 threads) ----
        const int bb = blockIdx.x - UVBLK;
        if (bb == 0 && tid < 64)
            v[(size_t)NN * D + tid] = 0xFF80;           // sentinel row = -inf
        int* hist  = (int*)WuT;            // [NBLK]
        int* fillb = (int*)WuT + 1024;     // [NBLK]
        int* baseb = (int*)WvT;            // [NBLK]
        for (int i = tid; i < NBLK; i += 512) { hist[i] = 0; fillb[i] = 0; }
        __syncthreads();

        // phase A: LDS histogram (4 passes x 512 threads x int4)
#pragma unroll 1
        for (int t = 0; t < 4; ++t) {
            int e = bb * EPB + t * 2048 + tid * 4;
            if (e < NE) {
                i32x4 d4 = *(const i32x4*)(ei + NE + e);
#pragma unroll
                for (int j = 0; j < 4; ++j)
                    atomicAdd(&hist[((unsigned int)d4[j]) >> 6], 1);
            }
        }
        __syncthreads();

        // phase B: one global atomicAdd per touched bucket
        for (int b = tid; b < NBLK; b += 512) {
            int h = hist[b];
            baseb[b] = h ? (int)atomicAdd(&cursor[b * CSTRIDE], (unsigned)h) : 0;
        }
        __syncthreads();

        // phase C: place edges (re-read, L1/L2 hot)
#pragma unroll 1
        for (int t = 0; t < 4; ++t) {
            int e = bb * EPB + t * 2048 + tid * 4;
            if (e < NE) {
                i32x4 s4 = *(const i32x4*)(ei + e);
                i32x4 d4 = *(const i32x4*)(ei + NE + e);
#pragma unroll
                for (int j = 0; j < 4; ++j) {
                    unsigned int de = (unsigned int)d4[j];
                    unsigned int b  = de >> 6;
                    int pos = baseb[b] + atomicAdd(&fillb[b], 1);
                    if (pos < BCAP)
                        bins[(size_t)b * BCAP + pos] =
                            (((unsigned int)s4[j]) << 6) | (de & 63u);
                }
            }
        }
    }
}

// ---------------------------------------------------------------------------
// slice: CSR build (all 512 threads) + unroll-1 row loop:
//   m = register max over neighbor v-rows; out = relu(u+m) + res.
// ---------------------------------------------------------------------------
__global__ __launch_bounds__(512) void slice_kernel(
    const unsigned short* __restrict__ u,
    const unsigned short* __restrict__ v,
    const unsigned short* __restrict__ res,
    const unsigned int* __restrict__ bins,
    const unsigned int* __restrict__ cursor,
    float* __restrict__ out)
{
    __shared__ int sorted[SCRTOT];     // src ids, CSR by row
    __shared__ int cntL[64], ofsL[64], fillL[64];

    const int tid  = threadIdx.x;
    const int lane = tid & 63;
    const int wid  = tid >> 6;                 // 0..7
    const int base = blockIdx.x * SLICE;

    if (tid < 64) { cntL[tid] = 0; fillL[tid] = 0; }
    __syncthreads();

    unsigned int cnt = cursor[blockIdx.x * CSTRIDE];
    if (cnt > BCAP) cnt = BCAP;
    const unsigned int* __restrict__ eb = bins + (size_t)blockIdx.x * BCAP;

    // ---- histogram by dst row (all threads) ----
    for (unsigned int i0 = tid; i0 < cnt; i0 += 512)
        atomicAdd(&cntL[eb[i0] & 63u], 1);
    __syncthreads();

    // ---- exclusive prefix scan of x4-rounded counts (wave 0) ----
    if (wid == 0) {
        int a = (cntL[lane] + 3) & ~3;
        int s = a;
#pragma unroll
        for (int off = 1; off < 64; off <<= 1) {
            int t = __shfl_up(s, off);
            if (lane >= off) s += t;
        }
        ofsL[lane] = s - a;
    }
    __syncthreads();

    // ---- scatter into CSR ----
    for (unsigned int i0 = tid; i0 < cnt; i0 += 512) {
        unsigned int e = eb[i0];
        int dl = (int)(e & 63u);
        int pos = ofsL[dl] + atomicAdd(&fillL[dl], 1);
        sorted[pos] = (int)(e >> 6);
    }
    __syncthreads();

    // ---- pad lists to x4 with sentinel (+4 tail for prefetch overread) ----
    if (tid < 64) {
        int c = cntL[tid], o = ofsL[tid];
        int a = (c + 3) & ~3;
        for (int j = c; j < a; ++j) sorted[o + j] = NN;
        if (tid == 63)
            for (int t = 0; t < 4; ++t) sorted[o + a + t] = NN;
    }
    __syncthreads();

    // ---- aggregate + trivial epilogue: 8 rows per wave, lane = column ----
#pragma unroll 1
    for (int i = 0; i < 8; ++i) {
        int r = wid * 8 + i;
        int n = base + r;
        if (n >= NN) break;
        float ur = b2f(u[(size_t)n * D + lane]);
        float rr = b2f(res[(size_t)n * D + lane]);
        const int o = ofsL[r];
        const int a = (cntL[r] + 3) & ~3;
        float m = -__builtin_inff();
        i32x4 idx = *(const i32x4*)&sorted[o];          // uniform broadcast
#pragma unroll 2
        for (int j = 0; j < a; j += 4) {
            i32x4 nx = *(const i32x4*)&sorted[o + j + 4];  // prefetch
            float v0 = b2f(v[(size_t)idx[0] * D + lane]);
            float v1 = b2f(v[(size_t)idx[1] * D + lane]);
            float v2 = b2f(v[(size_t)idx[2] * D + lane]);
            float v3 = b2f(v[(size_t)idx[3] * D + lane]);
            m = fmaxf(m, fmaxf(fmaxf(v0, v1), fmaxf(v2, v3)));
            idx = nx;
        }
        float agg = fmaxf(0.f, ur + m);   // relu; empty row -> -inf -> 0
        out[(size_t)n * D + lane] = agg + rr;
    }
}

extern "C" void kernel_launch(void* const* d_in, const int* in_sizes, int n_in,
                              void* d_out, int out_size, void* d_ws, size_t ws_size,
                              hipStream_t stream) {
    const float* x      = (const float*)d_in[0];
    const int*   ei     = (const int*)d_in[1];
    const float* W_edge = (const float*)d_in[2];
    const float* b_edge = (const float*)d_in[3];
    const float* W_res  = (const float*)d_in[4];
    const float* b_res  = (const float*)d_in[5];
    float* out = (float*)d_out;

    // ws: cursor u32[CURWORDS] (reserve 64KB) | bins u32[NBLK*BCAP] (4.8MB)
    //     | u bf16 (6.4MB) | v bf16 (6.4MB + sentinel row) | res bf16 (6.4MB)
    unsigned int*   cursor = (unsigned int*)d_ws;
    unsigned int*   bins   = (unsigned int*)((char*)d_ws + (1u << 16));
    unsigned short* uu     = (unsigned short*)((char*)d_ws + (1u << 16)
                              + (size_t)NBLK * BCAP * 4);
    unsigned short* vv     = uu + (size_t)NN * D;
    unsigned short* rr     = vv + (size_t)(NN + 1) * D;   // after sentinel row

    zero_cursor<<<(CURWORDS + 255) / 256, 256, 0, stream>>>(cursor);
    pre_fused<<<UVBLK + BINBLK, 512, 0, stream>>>(x, ei, W_edge, b_edge, W_res, b_res,
                                                  uu, vv, rr, bins, cursor);
    slice_kernel<<<NBLK, 512, 0, stream>>>(uu, vv, rr, bins, cursor, out);
}

// Round 22
// 63.068 us; speedup vs baseline: 5.5439x; 5.5439x over previous
//
#include <hip/hip_runtime.h>

#define NN 50000
#define NE 800000
#define D 64
#define SLICE 64                        // dst nodes per slice block
#define NBLK 782                        // ceil(NN/SLICE) = buckets
#define BCAP 1536                       // per-bucket capacity (mean 1024, >15 sigma)
#define CSTRIDE 4                       // cursor padding: 16 B
#define UVNODES 64                      // nodes per uv block (8 per wave, 8 waves)
#define UVBLK 782                       // ceil(NN/UVNODES)
#define BINBLK 98                       // fat bin blocks (8192 edges each)
#define EPB 8192                        // edges per bin block
#define SCRTOT 2304                     // sorted-list capacity
#define CURWORDS (NBLK * CSTRIDE)       // 3128 dwords
#define WS 68                           // W^T row stride (dwords); 68 mod 32 = 4 -> f32x4 start banks == contiguous-b128 pattern

typedef int i32x4 __attribute__((ext_vector_type(4)));
typedef float f32x4 __attribute__((ext_vector_type(4)));
typedef unsigned short u16x8 __attribute__((ext_vector_type(8)));

__device__ __forceinline__ float b2f(unsigned short h) {
    unsigned int u = ((unsigned int)h) << 16;
    return __builtin_bit_cast(float, u);
}
__device__ __forceinline__ unsigned short f2bf(float f) {
    unsigned int u = __builtin_bit_cast(unsigned int, f);
    u = (u + 0x7fffu + ((u >> 16) & 1u)) >> 16;
    return (unsigned short)u;
}

// ---------------------------------------------------------------------------
// zero_cursor: zeroes the per-bucket cursors.
// ---------------------------------------------------------------------------
__global__ __launch_bounds__(256) void zero_cursor(unsigned int* __restrict__ cursor)
{
    int i = blockIdx.x * 256 + threadIdx.x;
    if (i < CURWORDS) cursor[i] = 0u;
}

// ---------------------------------------------------------------------------
// pre_fused (512 threads): blocks [0, UVBLK) = uv/res GEMMs.
//   Same as r21 EXCEPT: kq loop is `#pragma unroll 2` — r21's full unroll
//   made LLVM hoist all 48 ds_read_b128s -> VGPR 128 + scratch spills
//   (FETCH 283MB/WRITE 469MB). Bounding the unroll caps live W-fragments
//   at 2 iterations (~60 VGPR total).
// Blocks [UVBLK, ..) = histogram binning (unchanged).
// LDS: 3 x 64*68 f32 (51K) + xs bf16 8K = 59 KB -> 2 blocks/CU, 16 waves.
// ---------------------------------------------------------------------------
__global__ __launch_bounds__(512) void pre_fused(
    const float* __restrict__ x,
    const int* __restrict__ ei,
    const float* __restrict__ W_edge,
    const float* __restrict__ b_edge,
    const float* __restrict__ W_res,
    const float* __restrict__ b_res,
    unsigned short* __restrict__ u,
    unsigned short* __restrict__ v,
    unsigned short* __restrict__ res,
    unsigned int* __restrict__ bins,
    unsigned int* __restrict__ cursor)
{
    __shared__ float WuT[D * WS];           // (Wtop-Wbot)^T [c][k] | bin: hist/fill
    __shared__ float WvT[D * WS];           // Wbot^T               | bin: base
    __shared__ float WrT[D * WS];           // W_res^T
    __shared__ unsigned short xs[8][D][8];  // [wave][k][node] bf16 (8 KB)

    const int tid  = threadIdx.x;
    const int lane = tid & 63;
    const int wid  = tid >> 6;              // 0..7

    if (blockIdx.x < UVBLK) {
        // stage W transposed (coalesced global reads; scatter LDS writes, one-time)
        for (int i = tid; i < D * D; i += 512) {
            int k = i >> 6, c = i & 63;
            float wt = W_edge[i], wb = W_edge[D * D + i];
            WuT[c * WS + k] = wt - wb;
            WvT[c * WS + k] = wb;
            WrT[c * WS + k] = W_res[i];
        }

        // stage x rows as bf16: lane l holds x[n0+j][l]; pack 8 -> one b128 write
        const int n0  = blockIdx.x * UVNODES + wid * 8;
        const int n0c = (n0 <= NN - 8) ? n0 : (NN - 8);
        {
            u16x8 px;
#pragma unroll
            for (int j = 0; j < 8; ++j)
                px[j] = f2bf(x[(size_t)(n0c + j) * D + lane]);
            *(u16x8*)&xs[wid][lane][0] = px;
        }
        __syncthreads();     // W ready (xs is wave-private; barrier covers both)

        const float be = b_edge[lane];
        const float br = b_res[lane];
        float au[8], av[8], ar[8];
#pragma unroll
        for (int j = 0; j < 8; ++j) { au[j] = be; av[j] = 0.f; ar[j] = br; }

#pragma unroll 2
        for (int kq = 0; kq < 16; ++kq) {
            f32x4 wu = *(const f32x4*)&WuT[lane * WS + 4 * kq];
            f32x4 wv = *(const f32x4*)&WvT[lane * WS + 4 * kq];
            f32x4 wr = *(const f32x4*)&WrT[lane * WS + 4 * kq];
#pragma unroll
            for (int t = 0; t < 4; ++t) {
                u16x8 xh = *(const u16x8*)&xs[wid][4 * kq + t][0];  // uniform
#pragma unroll
                for (int j = 0; j < 8; ++j) {
                    float s = b2f(xh[j]);
                    au[j] += s * wu[t];
                    av[j] += s * wv[t];
                    ar[j] += s * wr[t];
                }
            }
        }

        if (n0 < NN) {   // NN % 8 == 0 -> all 8 valid when n0 < NN
#pragma unroll
            for (int j = 0; j < 8; ++j) {
                u[(size_t)(n0 + j) * D + lane]   = f2bf(au[j]);
                v[(size_t)(n0 + j) * D + lane]   = f2bf(av[j]);
                res[(size_t)(n0 + j) * D + lane] = f2bf(ar[j]);
            }
        }
    } else {
        // ---- histogram binning (512 threads) ----
        const int bb = blockIdx.x - UVBLK;
        if (bb == 0 && tid < 64)
            v[(size_t)NN * D + tid] = 0xFF80;           // sentinel row = -inf
        int* hist  = (int*)WuT;            // [NBLK]
        int* fillb = (int*)WuT + 1024;     // [NBLK]
        int* baseb = (int*)WvT;            // [NBLK]
        for (int i = tid; i < NBLK; i += 512) { hist[i] = 0; fillb[i] = 0; }
        __syncthreads();

        // phase A: LDS histogram (4 passes x 512 threads x int4)
#pragma unroll 1
        for (int t = 0; t < 4; ++t) {
            int e = bb * EPB + t * 2048 + tid * 4;
            if (e < NE) {
                i32x4 d4 = *(const i32x4*)(ei + NE + e);
#pragma unroll
                for (int j = 0; j < 4; ++j)
                    atomicAdd(&hist[((unsigned int)d4[j]) >> 6], 1);
            }
        }
        __syncthreads();

        // phase B: one global atomicAdd per touched bucket
        for (int b = tid; b < NBLK; b += 512) {
            int h = hist[b];
            baseb[b] = h ? (int)atomicAdd(&cursor[b * CSTRIDE], (unsigned)h) : 0;
        }
        __syncthreads();

        // phase C: place edges (re-read, L1/L2 hot)
#pragma unroll 1
        for (int t = 0; t < 4; ++t) {
            int e = bb * EPB + t * 2048 + tid * 4;
            if (e < NE) {
                i32x4 s4 = *(const i32x4*)(ei + e);
                i32x4 d4 = *(const i32x4*)(ei + NE + e);
#pragma unroll
                for (int j = 0; j < 4; ++j) {
                    unsigned int de = (unsigned int)d4[j];
                    unsigned int b  = de >> 6;
                    int pos = baseb[b] + atomicAdd(&fillb[b], 1);
                    if (pos < BCAP)
                        bins[(size_t)b * BCAP + pos] =
                            (((unsigned int)s4[j]) << 6) | (de & 63u);
                }
            }
        }
    }
}

// ---------------------------------------------------------------------------
// slice: CSR build (all 512 threads) + unroll-1 row loop:
//   m = register max over neighbor v-rows; out = relu(u+m) + res.
// ---------------------------------------------------------------------------
__global__ __launch_bounds__(512) void slice_kernel(
    const unsigned short* __restrict__ u,
    const unsigned short* __restrict__ v,
    const unsigned short* __restrict__ res,
    const unsigned int* __restrict__ bins,
    const unsigned int* __restrict__ cursor,
    float* __restrict__ out)
{
    __shared__ int sorted[SCRTOT];     // src ids, CSR by row
    __shared__ int cntL[64], ofsL[64], fillL[64];

    const int tid  = threadIdx.x;
    const int lane = tid & 63;
    const int wid  = tid >> 6;                 // 0..7
    const int base = blockIdx.x * SLICE;

    if (tid < 64) { cntL[tid] = 0; fillL[tid] = 0; }
    __syncthreads();

    unsigned int cnt = cursor[blockIdx.x * CSTRIDE];
    if (cnt > BCAP) cnt = BCAP;
    const unsigned int* __restrict__ eb = bins + (size_t)blockIdx.x * BCAP;

    // ---- histogram by dst row (all threads) ----
    for (unsigned int i0 = tid; i0 < cnt; i0 += 512)
        atomicAdd(&cntL[eb[i0] & 63u], 1);
    __syncthreads();

    // ---- exclusive prefix scan of x4-rounded counts (wave 0) ----
    if (wid == 0) {
        int a = (cntL[lane] + 3) & ~3;
        int s = a;
#pragma unroll
        for (int off = 1; off < 64; off <<= 1) {
            int t = __shfl_up(s, off);
            if (lane >= off) s += t;
        }
        ofsL[lane] = s - a;
    }
    __syncthreads();

    // ---- scatter into CSR ----
    for (unsigned int i0 = tid; i0 < cnt; i0 += 512) {
        unsigned int e = eb[i0];
        int dl = (int)(e & 63u);
        int pos = ofsL[dl] + atomicAdd(&fillL[dl], 1);
        sorted[pos] = (int)(e >> 6);
    }
    __syncthreads();

    // ---- pad lists to x4 with sentinel (+4 tail for prefetch overread) ----
    if (tid < 64) {
        int c = cntL[tid], o = ofsL[tid];
        int a = (c + 3) & ~3;
        for (int j = c; j < a; ++j) sorted[o + j] = NN;
        if (tid == 63)
            for (int t = 0; t < 4; ++t) sorted[o + a + t] = NN;
    }
    __syncthreads();

    // ---- aggregate + trivial epilogue: 8 rows per wave, lane = column ----
#pragma unroll 1
    for (int i = 0; i < 8; ++i) {
        int r = wid * 8 + i;
        int n = base + r;
        if (n >= NN) break;
        float ur = b2f(u[(size_t)n * D + lane]);
        float rr = b2f(res[(size_t)n * D + lane]);
        const int o = ofsL[r];
        const int a = (cntL[r] + 3) & ~3;
        float m = -__builtin_inff();
        i32x4 idx = *(const i32x4*)&sorted[o];          // uniform broadcast
#pragma unroll 2
        for (int j = 0; j < a; j += 4) {
            i32x4 nx = *(const i32x4*)&sorted[o + j + 4];  // prefetch
            float v0 = b2f(v[(size_t)idx[0] * D + lane]);
            float v1 = b2f(v[(size_t)idx[1] * D + lane]);
            float v2 = b2f(v[(size_t)idx[2] * D + lane]);
            float v3 = b2f(v[(size_t)idx[3] * D + lane]);
            m = fmaxf(m, fmaxf(fmaxf(v0, v1), fmaxf(v2, v3)));
            idx = nx;
        }
        float agg = fmaxf(0.f, ur + m);   // relu; empty row -> -inf -> 0
        out[(size_t)n * D + lane] = agg + rr;
    }
}

extern "C" void kernel_launch(void* const* d_in, const int* in_sizes, int n_in,
                              void* d_out, int out_size, void* d_ws, size_t ws_size,
                              hipStream_t stream) {
    const float* x      = (const float*)d_in[0];
    const int*   ei     = (const int*)d_in[1];
    const float* W_edge = (const float*)d_in[2];
    const float* b_edge = (const float*)d_in[3];
    const float* W_res  = (const float*)d_in[4];
    const float* b_res  = (const float*)d_in[5];
    float* out = (float*)d_out;

    // ws: cursor u32[CURWORDS] (reserve 64KB) | bins u32[NBLK*BCAP] (4.8MB)
    //     | u bf16 (6.4MB) | v bf16 (6.4MB + sentinel row) | res bf16 (6.4MB)
    unsigned int*   cursor = (unsigned int*)d_ws;
    unsigned int*   bins   = (unsigned int*)((char*)d_ws + (1u << 16));
    unsigned short* uu     = (unsigned short*)((char*)d_ws + (1u << 16)
                              + (size_t)NBLK * BCAP * 4);
    unsigned short* vv     = uu + (size_t)NN * D;
    unsigned short* rr     = vv + (size_t)(NN + 1) * D;   // after sentinel row

    zero_cursor<<<(CURWORDS + 255) / 256, 256, 0, stream>>>(cursor);
    pre_fused<<<UVBLK + BINBLK, 512, 0, stream>>>(x, ei, W_edge, b_edge, W_res, b_res,
                                                  uu, vv, rr, bins, cursor);
    slice_kernel<<<NBLK, 512, 0, stream>>>(uu, vv, rr, bins, cursor, out);
}